// Round 4
// baseline (459.659 us; speedup 1.0000x reference)
//
#include <hip/hip_runtime.h>
#include <stdint.h>

#define N_CUST 500000
#define N_FUND 50000
#define N_EDGE 4000000
#define D_CUST 101
#define HID 64

#define NB   512                              // reorder blocks (measured-good)
#define EPB  ((N_EDGE + NB - 1) / NB)         // 7813 edges per block
#define CB   512                              // customers per bucket
#define NBKT ((N_CUST + CB - 1) / CB)         // 977 buckets
#define CAP  5120                             // per-bucket capacity (mean 4096, +16 sigma)
#define GPAD 32                               // gcur padding: 1 counter per 128B line

typedef float float4u __attribute__((ext_vector_type(4), aligned(4)));
using frag_ab = __attribute__((ext_vector_type(8))) short;   // 8 bf16
using frag_cd = __attribute__((ext_vector_type(4))) float;   // 4 f32

struct __align__(16) Accum { float g0, g1, cnt, pad; };

__device__ __forceinline__ short f2bf(float f) {
    unsigned u = __float_as_uint(f);
    u += 0x7fffu + ((u >> 16) & 1u);          // round-to-nearest-even
    return (short)(u >> 16);
}

// ---------------------------------------------------------------------------
// k_gf: gf[f] = relu(x_f[f]*W_fund + b_fund) @ (W_l @ W_out)
// Block 0 additionally precomputes Bt = W_r@W_out, c2 = b_l@W_out + b_out,
// wcb = W_cust in bf16 MFMA B-fragment layout, and zeroes gcur (padded).
// Optional Az != nullptr: zero the 8MB Accum array (fallback path only).
// ---------------------------------------------------------------------------
__global__ __launch_bounds__(256) void k_gf(
    const float* __restrict__ x_fund,
    const float* __restrict__ W_fund,
    const float* __restrict__ b_fund,
    const float* __restrict__ W_l,
    const float* __restrict__ W_r,
    const float* __restrict__ W_out,
    const float* __restrict__ Wc,
    const float* __restrict__ b_l,
    const float* __restrict__ b_out,
    float2* __restrict__ gf,
    frag_ab* __restrict__ wcb,
    float* __restrict__ Bt,
    float* __restrict__ c2,
    unsigned* __restrict__ gcur,
    float4* __restrict__ Az)
{
    __shared__ float sAf[128];
    __shared__ float sWf[64];
    __shared__ float sBf[64];
    int t = threadIdx.x;

    if (Az != nullptr) {
        float4 z4 = make_float4(0.f, 0.f, 0.f, 0.f);
        for (int i = blockIdx.x * 256 + t; i < N_CUST; i += gridDim.x * 256)
            Az[i] = z4;
    }

    if (t < 128) {
        int h = t >> 1, j = t & 1;
        float s = 0.f;
        for (int k = 0; k < 64; ++k)
            s = fmaf(W_l[h * 64 + k], W_out[k * 2 + j], s);
        sAf[t] = s;
    } else if (t < 192) {
        sWf[t - 128] = W_fund[t - 128];
    } else {
        sBf[t - 192] = b_fund[t - 192];
    }
    __syncthreads();

    int f = blockIdx.x * 256 + t;
    if (f < N_FUND) {
        float xf = x_fund[f];
        float g0 = 0.f, g1 = 0.f;
        #pragma unroll
        for (int h = 0; h < 64; ++h) {
            float hf = fmaxf(fmaf(xf, sWf[h], sBf[h]), 0.f);
            g0 = fmaf(hf, sAf[2 * h + 0], g0);
            g1 = fmaf(hf, sAf[2 * h + 1], g1);
        }
        gf[f] = make_float2(g0, g1);
    }

    if (blockIdx.x == 0) {
        for (int k = t; k < NBKT * GPAD; k += 256) gcur[k] = 0u;
        if (t < 128) {
            int h = t >> 1, j = t & 1;
            float s = 0.f;
            for (int k = 0; k < 64; ++k)
                s = fmaf(W_r[h * 64 + k], W_out[k * 2 + j], s);
            Bt[t] = s;
        } else if (t < 130) {
            int j = t - 128;
            float s = b_out[j];
            for (int k = 0; k < 64; ++k)
                s = fmaf(b_l[k], W_out[k * 2 + j], s);
            c2[j] = s;
        }
        // wcb[(nt*4+kc)*64 + lane] = B-fragment for that (nt,kc,lane)
        for (int sidx = t; sidx < 1024; sidx += 256) {
            int fidx = sidx >> 6, l = sidx & 63;
            int c = l & 15, q = l >> 4;
            int nt = fidx >> 2, kc = fidx & 3;
            frag_ab fr;
            #pragma unroll
            for (int j = 0; j < 8; ++j) {
                int kk = kc * 32 + q * 8 + j;
                int h  = nt * 16 + c;
                fr[j] = (kk < D_CUST) ? f2bf(Wc[kk * HID + h]) : (short)0;
            }
            wcb[sidx] = fr;
        }
    }
}

// ---------------------------------------------------------------------------
// k_reorder v2: LDS bucket-sort of each block's 7813 edges.
// rec = src | (dst_local << 16); bucket = dst >> 9; dl = dst & 511.
// Changes vs measured-good R0 version:
//  - no ldsBkt array: flush walks per-bucket runs via localOff/cur
//    (LDS 62.5 -> 46.9 KB => 3 blocks/CU instead of 2)
//  - gcur padded to 1 counter / 128B (reserve atomics were false-sharing
//    16 counters/line across 512 blocks)
// ---------------------------------------------------------------------------
__global__ __launch_bounds__(256) void k_reorder(
    const int* __restrict__ src, const int* __restrict__ dst,
    unsigned* __restrict__ gcur, unsigned* __restrict__ recs)
{
    __shared__ unsigned hist[NBKT];
    __shared__ unsigned localOff[NBKT];
    __shared__ unsigned cur[NBKT];
    __shared__ unsigned baseG[NBKT];
    __shared__ unsigned ldsRec[EPB];

    int t = threadIdx.x, b = blockIdx.x;
    int e0 = b * EPB, e1 = min(e0 + EPB, N_EDGE);

    for (int k = t; k < NBKT; k += 256) hist[k] = 0;
    __syncthreads();
    for (int e = e0 + t; e < e1; e += 256)
        atomicAdd(&hist[((unsigned)dst[e]) >> 9], 1u);
    __syncthreads();

    // one-wave exclusive scan of hist[0..NBKT)
    if (t < 64) {
        unsigned v[16], pre[16], run = 0;
        #pragma unroll
        for (int j = 0; j < 16; ++j) {
            int idx = t * 16 + j;
            v[j] = (idx < NBKT) ? hist[idx] : 0u;
            pre[j] = run; run += v[j];
        }
        unsigned sc = run;
        #pragma unroll
        for (int d = 1; d < 64; d <<= 1) {
            unsigned n = __shfl_up(sc, d, 64);
            if (t >= d) sc += n;
        }
        unsigned lane_excl = sc - run;
        #pragma unroll
        for (int j = 0; j < 16; ++j) {
            int idx = t * 16 + j;
            if (idx < NBKT) {
                localOff[idx] = lane_excl + pre[j];
                cur[idx]      = lane_excl + pre[j];
            }
        }
    }
    __syncthreads();

    // reserve global chunks (one atomic per non-empty bucket, padded counter)
    for (int k = t; k < NBKT; k += 256) {
        unsigned h = hist[k];
        baseG[k] = h ? ((unsigned)k * CAP + atomicAdd(&gcur[k * GPAD], h)) : 0u;
    }

    // LDS scatter (bucket-sorted placement)
    for (int e = e0 + t; e < e1; e += 256) {
        unsigned d = (unsigned)dst[e];
        unsigned s = (unsigned)src[e];
        unsigned k = d >> 9;
        unsigned p = atomicAdd(&cur[k], 1u);
        ldsRec[p] = s | ((d & 511u) << 16);
    }
    __syncthreads();

    // per-bucket run flush: thread t owns buckets t, t+256, ...
    // each run is ~8 consecutive LDS words -> one 32B global burst
    for (int k = t; k < NBKT; k += 256) {
        unsigned i0 = localOff[k], i1 = cur[k];
        unsigned g = baseG[k];
        unsigned gend = ((unsigned)k + 1u) * CAP;
        for (unsigned i = i0; i < i1 && g < gend; ++i, ++g)
            recs[g] = ldsRec[i];
    }
}

// ---------------------------------------------------------------------------
// k_bucket v2: fused per-bucket aggregate + MFMA GEMM + epilogue, 512 threads.
// Phase A: accumulate records into LDS (s0,s1,scn), 512-way.
// Phase B: 8 waves x 4 tiles: z = relu(x@Wc+bc); out = mean + z@Bt + c2.
// B-fragments come precomputed from wcb (16 dwordx4/thread, no scalar Wc walk).
// ---------------------------------------------------------------------------
__global__ __launch_bounds__(512) void k_bucket(
    const unsigned* __restrict__ recs, const unsigned* __restrict__ gcur,
    const float2* __restrict__ gf,
    const float* __restrict__ x, const float* __restrict__ bc,
    const frag_ab* __restrict__ wcb, const float* __restrict__ Bt,
    const float* __restrict__ c2,
    float2* __restrict__ out)
{
    __shared__ float s0[CB], s1[CB], scn[CB];
    __shared__ float sBt[128];
    __shared__ float zb[8][16 * 68];

    int t = threadIdx.x, k = blockIdx.x;
    int w = t >> 6, lane = t & 63;
    int c = lane & 15, q = lane >> 4;
    float* z = zb[w];

    if (t < 128) sBt[t] = Bt[t];
    for (int cc = t; cc < CB; cc += 512) { s0[cc] = 0.f; s1[cc] = 0.f; scn[cc] = 0.f; }
    __syncthreads();

    // phase A: aggregate this bucket's records
    unsigned n = min(gcur[(unsigned)k * GPAD], (unsigned)CAP);
    unsigned r0 = (unsigned)k * CAP;
    for (unsigned i = r0 + t; i < r0 + n; i += 512) {
        unsigned r = recs[i];
        float2 g = gf[r & 0xFFFFu];
        unsigned dl = r >> 16;
        atomicAdd(&s0[dl], g.x);
        atomicAdd(&s1[dl], g.y);
        atomicAdd(&scn[dl], 1.f);
    }

    // independent global loads issue while phase-A atomics drain
    frag_ab bfrag[16];
    #pragma unroll
    for (int f = 0; f < 16; ++f) bfrag[f] = wcb[f * 64 + lane];
    float bcv[4];
    #pragma unroll
    for (int nt = 0; nt < 4; ++nt) bcv[nt] = bc[nt * 16 + c];
    float c20 = c2[0], c21 = c2[1];
    __syncthreads();

    int cust0 = k * CB;
    int n_tiles = min(CB / 16, (N_CUST - cust0) >> 4);   // 32, or 18 for last

    // phase B: wave w takes tiles w, w+8, ...
    for (int tl = w; tl < n_tiles; tl += 8) {
        int lrow = tl * 16 + c;
        int row = cust0 + lrow;
        const float* xr = x + (size_t)row * D_CUST;
        frag_ab af[4];
        #pragma unroll
        for (int kc = 0; kc < 3; ++kc) {
            float4u lo = *(const float4u*)(xr + kc * 32 + q * 8);
            float4u hi = *(const float4u*)(xr + kc * 32 + q * 8 + 4);
            frag_ab f;
            f[0]=f2bf(lo[0]); f[1]=f2bf(lo[1]); f[2]=f2bf(lo[2]); f[3]=f2bf(lo[3]);
            f[4]=f2bf(hi[0]); f[5]=f2bf(hi[1]); f[6]=f2bf(hi[2]); f[7]=f2bf(hi[3]);
            af[kc] = f;
        }
        {   // tail k = 96..127: only q==0 lanes hold valid k (96..100)
            frag_ab f = {0,0,0,0,0,0,0,0};
            if (q == 0) {
                float4u lo = *(const float4u*)(xr + 96);
                f[0]=f2bf(lo[0]); f[1]=f2bf(lo[1]); f[2]=f2bf(lo[2]); f[3]=f2bf(lo[3]);
                f[4]=f2bf(xr[100]);
            }
            af[3] = f;
        }
        frag_cd acc[4];
        #pragma unroll
        for (int nt = 0; nt < 4; ++nt)
            acc[nt] = (frag_cd){bcv[nt], bcv[nt], bcv[nt], bcv[nt]};
        #pragma unroll
        for (int kc = 0; kc < 4; ++kc)
            #pragma unroll
            for (int nt = 0; nt < 4; ++nt)
                acc[nt] = __builtin_amdgcn_mfma_f32_16x16x32_bf16(
                    af[kc], bfrag[nt * 4 + kc], acc[nt], 0, 0, 0);

        // relu -> LDS: C[r = q*4+i][col = nt*16+c]
        #pragma unroll
        for (int nt = 0; nt < 4; ++nt)
            #pragma unroll
            for (int i = 0; i < 4; ++i)
                z[(q * 4 + i) * 68 + nt * 16 + c] = fmaxf(acc[nt][i], 0.f);

        // lane: z-row r=c, h in [q*16, q*16+16); reduce over q via shfl
        float p0 = 0.f, p1 = 0.f;
        #pragma unroll
        for (int j4 = 0; j4 < 4; ++j4) {
            float4u zv = *(const float4u*)(z + c * 68 + q * 16 + j4 * 4);
            float4u b0 = *(const float4u*)(sBt + q * 32 + j4 * 8);
            float4u b1 = *(const float4u*)(sBt + q * 32 + j4 * 8 + 4);
            p0 = fmaf(zv[0], b0[0], p0); p1 = fmaf(zv[0], b0[1], p1);
            p0 = fmaf(zv[1], b0[2], p0); p1 = fmaf(zv[1], b0[3], p1);
            p0 = fmaf(zv[2], b1[0], p0); p1 = fmaf(zv[2], b1[1], p1);
            p0 = fmaf(zv[3], b1[2], p0); p1 = fmaf(zv[3], b1[3], p1);
        }
        p0 += __shfl_xor(p0, 16, 64); p0 += __shfl_xor(p0, 32, 64);
        p1 += __shfl_xor(p1, 16, 64); p1 += __shfl_xor(p1, 32, 64);
        if (q == 0) {
            float inv = 1.0f / fmaxf(scn[lrow], 1.0f);
            out[row] = make_float2(fmaf(s0[lrow], inv, p0 + c20),
                                   fmaf(s1[lrow], inv, p1 + c21));
        }
    }
}

// ---------------------------------------------------------------------------
// Fallback-path kernels (direct global atomics) if ws too small for recs.
// ---------------------------------------------------------------------------
__global__ __launch_bounds__(256) void k_scatter_direct(
    const int* __restrict__ src, const int* __restrict__ dst,
    const float2* __restrict__ gf, Accum* __restrict__ A)
{
    int stride = gridDim.x * 256;
    for (int e = blockIdx.x * 256 + threadIdx.x; e < N_EDGE; e += stride) {
        int s = src[e], d = dst[e];
        float2 g = gf[s];
        unsafeAtomicAdd(&A[d].g0, g.x);
        unsafeAtomicAdd(&A[d].g1, g.y);
        unsafeAtomicAdd(&A[d].cnt, 1.0f);
    }
}

__global__ __launch_bounds__(256) void k_mean(
    const Accum* __restrict__ A, float2* __restrict__ mean2)
{
    int i = blockIdx.x * 256 + threadIdx.x;
    if (i < N_CUST) {
        Accum a = A[i];
        float inv = 1.0f / fmaxf(a.cnt, 1.0f);
        mean2[i] = make_float2(a.g0 * inv, a.g1 * inv);
    }
}

__global__ __launch_bounds__(256) void k_gemm(
    const float* __restrict__ x, const float* __restrict__ bc,
    const frag_ab* __restrict__ wcb, const float* __restrict__ Bt,
    const float* __restrict__ c2, const float2* __restrict__ mean2,
    float2* __restrict__ out)
{
    __shared__ float sBt[128];
    __shared__ float zb[4][16 * 68];

    int t = threadIdx.x;
    int w = t >> 6, lane = t & 63;
    int c = lane & 15, q = lane >> 4;
    float* z = zb[w];

    if (t < 128) sBt[t] = Bt[t];
    frag_ab bfrag[16];
    #pragma unroll
    for (int f = 0; f < 16; ++f) bfrag[f] = wcb[f * 64 + lane];
    float bcv[4];
    #pragma unroll
    for (int nt = 0; nt < 4; ++nt) bcv[nt] = bc[nt * 16 + c];
    float c20 = c2[0], c21 = c2[1];
    __syncthreads();

    const int NT = N_CUST / 16;
    for (int tl = blockIdx.x * 4 + w; tl < NT; tl += gridDim.x * 4) {
        int row0 = tl * 16;
        const float* xr = x + (size_t)(row0 + c) * D_CUST;
        frag_ab af[4];
        #pragma unroll
        for (int kc = 0; kc < 3; ++kc) {
            float4u lo = *(const float4u*)(xr + kc * 32 + q * 8);
            float4u hi = *(const float4u*)(xr + kc * 32 + q * 8 + 4);
            frag_ab f;
            f[0]=f2bf(lo[0]); f[1]=f2bf(lo[1]); f[2]=f2bf(lo[2]); f[3]=f2bf(lo[3]);
            f[4]=f2bf(hi[0]); f[5]=f2bf(hi[1]); f[6]=f2bf(hi[2]); f[7]=f2bf(hi[3]);
            af[kc] = f;
        }
        {
            frag_ab f = {0,0,0,0,0,0,0,0};
            if (q == 0) {
                float4u lo = *(const float4u*)(xr + 96);
                f[0]=f2bf(lo[0]); f[1]=f2bf(lo[1]); f[2]=f2bf(lo[2]); f[3]=f2bf(lo[3]);
                f[4]=f2bf(xr[100]);
            }
            af[3] = f;
        }
        frag_cd acc[4];
        #pragma unroll
        for (int nt = 0; nt < 4; ++nt)
            acc[nt] = (frag_cd){bcv[nt], bcv[nt], bcv[nt], bcv[nt]};
        #pragma unroll
        for (int kc = 0; kc < 4; ++kc)
            #pragma unroll
            for (int nt = 0; nt < 4; ++nt)
                acc[nt] = __builtin_amdgcn_mfma_f32_16x16x32_bf16(
                    af[kc], bfrag[nt * 4 + kc], acc[nt], 0, 0, 0);
        #pragma unroll
        for (int nt = 0; nt < 4; ++nt)
            #pragma unroll
            for (int i = 0; i < 4; ++i)
                z[(q * 4 + i) * 68 + nt * 16 + c] = fmaxf(acc[nt][i], 0.f);
        float p0 = 0.f, p1 = 0.f;
        #pragma unroll
        for (int j4 = 0; j4 < 4; ++j4) {
            float4u zv = *(const float4u*)(z + c * 68 + q * 16 + j4 * 4);
            float4u b0 = *(const float4u*)(sBt + q * 32 + j4 * 8);
            float4u b1 = *(const float4u*)(sBt + q * 32 + j4 * 8 + 4);
            p0 = fmaf(zv[0], b0[0], p0); p1 = fmaf(zv[0], b0[1], p1);
            p0 = fmaf(zv[1], b0[2], p0); p1 = fmaf(zv[1], b0[3], p1);
            p0 = fmaf(zv[2], b1[0], p0); p1 = fmaf(zv[2], b1[1], p1);
            p0 = fmaf(zv[3], b1[2], p0); p1 = fmaf(zv[3], b1[3], p1);
        }
        p0 += __shfl_xor(p0, 16, 64); p0 += __shfl_xor(p0, 32, 64);
        p1 += __shfl_xor(p1, 16, 64); p1 += __shfl_xor(p1, 32, 64);
        if (q == 0) {
            float2 m = mean2[row0 + c];
            out[row0 + c] = make_float2(p0 + c20 + m.x, p1 + c21 + m.y);
        }
    }
}

// ---------------------------------------------------------------------------
extern "C" void kernel_launch(void* const* d_in, const int* in_sizes, int n_in,
                              void* d_out, int out_size, void* d_ws, size_t ws_size,
                              hipStream_t stream) {
    const float* x_customer = (const float*)d_in[0];
    const float* x_fund     = (const float*)d_in[1];
    const int*   src_fund   = (const int*)d_in[2];
    const int*   dst_cust   = (const int*)d_in[3];
    const float* W_cust     = (const float*)d_in[4];
    const float* b_cust     = (const float*)d_in[5];
    const float* W_fund     = (const float*)d_in[6];
    const float* b_fund     = (const float*)d_in[7];
    const float* W_l        = (const float*)d_in[8];
    const float* b_l        = (const float*)d_in[9];
    const float* W_r        = (const float*)d_in[10];
    const float* W_out      = (const float*)d_in[11];
    const float* b_out      = (const float*)d_in[12];

    char* ws = (char*)d_ws;
    // fast path layout:
    //   recs @ 0          : 977*5120*4 = 20,008,960
    //   gf   @ 20,008,960 :   400,000
    //   wcb  @ 20,408,960 :    16,384
    //   Bt   @ 20,425,344 :       512
    //   c2   @ 20,425,856 :        64
    //   gcur @ 20,425,920 :   125,056  (977*32*4, padded) -> total 20,550,976
    const size_t NEED_FAST = 20550976ull;

    if (ws_size >= NEED_FAST) {
        unsigned* recs = (unsigned*)(ws);
        float2*   gf   = (float2*)  (ws + 20008960);
        frag_ab*  wcb  = (frag_ab*) (ws + 20408960);
        float*    Bt   = (float*)   (ws + 20425344);
        float*    c2   = (float*)   (ws + 20425856);
        unsigned* gcur = (unsigned*)(ws + 20425920);

        k_gf<<<256, 256, 0, stream>>>(
            x_fund, W_fund, b_fund, W_l, W_r, W_out, W_cust, b_l, b_out,
            gf, wcb, Bt, c2, gcur, nullptr);
        k_reorder<<<NB, 256, 0, stream>>>(src_fund, dst_cust, gcur, recs);
        k_bucket<<<NBKT, 512, 0, stream>>>(
            recs, gcur, gf, x_customer, b_cust, wcb, Bt, c2, (float2*)d_out);
    } else {
        // fallback: A 8,000,000 | mean2 4,000,000 | gf 400,000 | wcb 16,384
        //           | Bt 512 | c2 64 | gcur 125,056 -> 12,541,?  (fits 16MB)
        Accum*    A    = (Accum*)   (ws);
        float2*   mn2  = (float2*)  (ws + 8000000);
        float2*   gf   = (float2*)  (ws + 12000000);
        frag_ab*  wcb  = (frag_ab*) (ws + 12400000);
        float*    Bt   = (float*)   (ws + 12416384);
        float*    c2   = (float*)   (ws + 12416896);
        unsigned* gcur = (unsigned*)(ws + 12416960);

        k_gf<<<256, 256, 0, stream>>>(
            x_fund, W_fund, b_fund, W_l, W_r, W_out, W_cust, b_l, b_out,
            gf, wcb, Bt, c2, gcur, (float4*)A);
        k_scatter_direct<<<2048, 256, 0, stream>>>(src_fund, dst_cust, gf, A);
        k_mean<<<(N_CUST + 255) / 256, 256, 0, stream>>>(A, mn2);
        k_gemm<<<2048, 256, 0, stream>>>(
            x_customer, b_cust, wcb, Bt, c2, mn2, (float2*)d_out);
    }
}

// Round 5
// 420.289 us; speedup vs baseline: 1.0937x; 1.0937x over previous
//
#include <hip/hip_runtime.h>
#include <stdint.h>

#define N_CUST 500000
#define N_FUND 50000
#define N_EDGE 4000000
#define D_CUST 101
#define HID 64

#define NB   512                              // reorder blocks (measured-good R0)
#define EPB  ((N_EDGE + NB - 1) / NB)         // 7813 edges per block
#define CB   512                              // customers per bucket
#define NBKT ((N_CUST + CB - 1) / CB)         // 977 buckets
#define CAP  5120                             // per-bucket capacity (mean 4096, +16 sigma)
#define GPAD 32                               // gcur padding: 1 counter per 128B line

typedef float float4u __attribute__((ext_vector_type(4), aligned(4)));
using frag_ab = __attribute__((ext_vector_type(8))) short;   // 8 bf16
using frag_cd = __attribute__((ext_vector_type(4))) float;   // 4 f32

struct __align__(16) Accum { float g0, g1, cnt, pad; };

__device__ __forceinline__ short f2bf(float f) {
    unsigned u = __float_as_uint(f);
    u += 0x7fffu + ((u >> 16) & 1u);          // round-to-nearest-even
    return (short)(u >> 16);
}

// ---------------------------------------------------------------------------
// k_gf: gf[f] = relu(x_f[f]*W_fund + b_fund) @ (W_l @ W_out)
// Block 0 additionally precomputes Bt = W_r@W_out, c2 = b_l@W_out + b_out,
// wcb = W_cust in bf16 MFMA B-fragment layout, and zeroes gcur (padded).
// Optional Az != nullptr: zero the 8MB Accum array (fallback path only).
// ---------------------------------------------------------------------------
__global__ __launch_bounds__(256) void k_gf(
    const float* __restrict__ x_fund,
    const float* __restrict__ W_fund,
    const float* __restrict__ b_fund,
    const float* __restrict__ W_l,
    const float* __restrict__ W_r,
    const float* __restrict__ W_out,
    const float* __restrict__ Wc,
    const float* __restrict__ b_l,
    const float* __restrict__ b_out,
    float2* __restrict__ gf,
    frag_ab* __restrict__ wcb,
    float* __restrict__ Bt,
    float* __restrict__ c2,
    unsigned* __restrict__ gcur,
    float4* __restrict__ Az)
{
    __shared__ float sAf[128];
    __shared__ float sWf[64];
    __shared__ float sBf[64];
    int t = threadIdx.x;

    if (Az != nullptr) {
        float4 z4 = make_float4(0.f, 0.f, 0.f, 0.f);
        for (int i = blockIdx.x * 256 + t; i < N_CUST; i += gridDim.x * 256)
            Az[i] = z4;
    }

    if (t < 128) {
        int h = t >> 1, j = t & 1;
        float s = 0.f;
        for (int k = 0; k < 64; ++k)
            s = fmaf(W_l[h * 64 + k], W_out[k * 2 + j], s);
        sAf[t] = s;
    } else if (t < 192) {
        sWf[t - 128] = W_fund[t - 128];
    } else {
        sBf[t - 192] = b_fund[t - 192];
    }
    __syncthreads();

    int f = blockIdx.x * 256 + t;
    if (f < N_FUND) {
        float xf = x_fund[f];
        float g0 = 0.f, g1 = 0.f;
        #pragma unroll
        for (int h = 0; h < 64; ++h) {
            float hf = fmaxf(fmaf(xf, sWf[h], sBf[h]), 0.f);
            g0 = fmaf(hf, sAf[2 * h + 0], g0);
            g1 = fmaf(hf, sAf[2 * h + 1], g1);
        }
        gf[f] = make_float2(g0, g1);
    }

    if (blockIdx.x == 0) {
        for (int k = t; k < NBKT * GPAD; k += 256) gcur[k] = 0u;
        if (t < 128) {
            int h = t >> 1, j = t & 1;
            float s = 0.f;
            for (int k = 0; k < 64; ++k)
                s = fmaf(W_r[h * 64 + k], W_out[k * 2 + j], s);
            Bt[t] = s;
        } else if (t < 130) {
            int j = t - 128;
            float s = b_out[j];
            for (int k = 0; k < 64; ++k)
                s = fmaf(b_l[k], W_out[k * 2 + j], s);
            c2[j] = s;
        }
        // wcb[(nt*4+kc)*64 + lane] = B-fragment for that (nt,kc,lane)
        for (int sidx = t; sidx < 1024; sidx += 256) {
            int fidx = sidx >> 6, l = sidx & 63;
            int c = l & 15, q = l >> 4;
            int nt = fidx >> 2, kc = fidx & 3;
            frag_ab fr;
            #pragma unroll
            for (int j = 0; j < 8; ++j) {
                int kk = kc * 32 + q * 8 + j;
                int h  = nt * 16 + c;
                fr[j] = (kk < D_CUST) ? f2bf(Wc[kk * HID + h]) : (short)0;
            }
            wcb[sidx] = fr;
        }
    }
}

// ---------------------------------------------------------------------------
// k_reorder: exact R0 (measured ~55us) flush structure: LDS bucket-sort of
// each block's 7813 edges, contiguous global chunk reservation per bucket,
// coalesced flush via ldsBkt. Only change vs R0: gcur padded (GPAD).
// rec = src | (dst_local << 16); bucket = dst >> 9; dl = dst & 511.
// ---------------------------------------------------------------------------
__global__ __launch_bounds__(256) void k_reorder(
    const int* __restrict__ src, const int* __restrict__ dst,
    unsigned* __restrict__ gcur, unsigned* __restrict__ recs)
{
    __shared__ unsigned hist[NBKT];
    __shared__ unsigned localOff[NBKT];
    __shared__ unsigned cur[NBKT];
    __shared__ unsigned baseG[NBKT];
    __shared__ unsigned ldsRec[EPB];
    __shared__ unsigned short ldsBkt[EPB];

    int t = threadIdx.x, b = blockIdx.x;
    int e0 = b * EPB, e1 = min(e0 + EPB, N_EDGE);
    int cntE = e1 - e0;

    for (int k = t; k < NBKT; k += 256) hist[k] = 0;
    __syncthreads();
    for (int e = e0 + t; e < e1; e += 256)
        atomicAdd(&hist[((unsigned)dst[e]) >> 9], 1u);
    __syncthreads();

    // one-wave exclusive scan of hist[0..NBKT)
    if (t < 64) {
        unsigned v[16], pre[16], run = 0;
        #pragma unroll
        for (int j = 0; j < 16; ++j) {
            int idx = t * 16 + j;
            v[j] = (idx < NBKT) ? hist[idx] : 0u;
            pre[j] = run; run += v[j];
        }
        unsigned sc = run;
        #pragma unroll
        for (int d = 1; d < 64; d <<= 1) {
            unsigned n = __shfl_up(sc, d, 64);
            if (t >= d) sc += n;
        }
        unsigned lane_excl = sc - run;
        #pragma unroll
        for (int j = 0; j < 16; ++j) {
            int idx = t * 16 + j;
            if (idx < NBKT) {
                localOff[idx] = lane_excl + pre[j];
                cur[idx]      = lane_excl + pre[j];
            }
        }
    }
    __syncthreads();

    // reserve global chunks (one atomic per non-empty bucket, padded counter)
    for (int k = t; k < NBKT; k += 256) {
        unsigned h = hist[k];
        baseG[k] = h ? ((unsigned)k * CAP + atomicAdd(&gcur[k * GPAD], h)) : 0u;
    }

    // LDS scatter
    for (int e = e0 + t; e < e1; e += 256) {
        unsigned d = (unsigned)dst[e];
        unsigned s = (unsigned)src[e];
        unsigned k = d >> 9;
        unsigned p = atomicAdd(&cur[k], 1u);
        ldsRec[p] = s | ((d & 511u) << 16);
        ldsBkt[p] = (unsigned short)k;
    }
    __syncthreads();

    // coalesced flush (bucket-sorted order -> consecutive i = consecutive g)
    for (int i = t; i < cntE; i += 256) {
        unsigned k = ldsBkt[i];
        unsigned g = baseG[k] + (i - localOff[k]);
        if (g < (k + 1u) * CAP) recs[g] = ldsRec[i];
    }
}

// ---------------------------------------------------------------------------
// k_bucket v3: 256 threads, wave-split concurrency.
//  wave 3  : aggregates this bucket's records into LDS (s0,s1,scn) with
//            uint4-vectorized recs reads (4 gf gathers in flight / group).
//  waves 0-2: MFMA GEMM tiles (stride 3): z = relu(x@Wc+bc);
//            pbuf[row] = z@Bt + c2.
//  Single barrier, then 256-thread epilogue: out = pbuf + (s/cnt).
// LDS 23.8 KB -> 6 blocks/CU (restores R0 residency; R4's 41.5KB halved it).
// ---------------------------------------------------------------------------
__global__ __launch_bounds__(256) void k_bucket(
    const unsigned* __restrict__ recs, const unsigned* __restrict__ gcur,
    const float2* __restrict__ gf,
    const float* __restrict__ x, const float* __restrict__ bc,
    const frag_ab* __restrict__ wcb, const float* __restrict__ Bt,
    const float* __restrict__ c2,
    float2* __restrict__ out)
{
    __shared__ float s0[CB], s1[CB], scn[CB];   // 6 KB
    __shared__ float sBt[128];                  // 0.5 KB
    __shared__ float pbuf[2 * CB];              // 4 KB
    __shared__ float zb[3][16 * 68];            // 13.1 KB

    int t = threadIdx.x, k = blockIdx.x;
    int w = t >> 6, lane = t & 63;
    int c = lane & 15, q = lane >> 4;

    if (t < 128) sBt[t] = Bt[t];
    for (int cc = t; cc < CB; cc += 256) { s0[cc] = 0.f; s1[cc] = 0.f; scn[cc] = 0.f; }
    __syncthreads();

    int cust0 = k * CB;
    int ncust = min(CB, N_CUST - cust0);
    int n_tiles = ncust >> 4;                   // 32, or 18 for last bucket

    if (w == 3) {
        // ------------ aggregation wave ------------
        unsigned n = min(gcur[(unsigned)k * GPAD], (unsigned)CAP);
        const unsigned* rp = recs + (size_t)k * CAP;
        unsigned i = (unsigned)lane * 4u;
        for (; i + 4u <= n; i += 256u) {
            uint4 rr = *(const uint4*)(rp + i);
            float2 ga = gf[rr.x & 0xFFFFu];
            float2 gb = gf[rr.y & 0xFFFFu];
            float2 gc = gf[rr.z & 0xFFFFu];
            float2 gd = gf[rr.w & 0xFFFFu];
            unsigned da = rr.x >> 16, db = rr.y >> 16;
            unsigned dc = rr.z >> 16, dd = rr.w >> 16;
            atomicAdd(&s0[da], ga.x); atomicAdd(&s1[da], ga.y); atomicAdd(&scn[da], 1.f);
            atomicAdd(&s0[db], gb.x); atomicAdd(&s1[db], gb.y); atomicAdd(&scn[db], 1.f);
            atomicAdd(&s0[dc], gc.x); atomicAdd(&s1[dc], gc.y); atomicAdd(&scn[dc], 1.f);
            atomicAdd(&s0[dd], gd.x); atomicAdd(&s1[dd], gd.y); atomicAdd(&scn[dd], 1.f);
        }
        // tail (n & 3 leftover records)
        unsigned base = n & ~3u;
        if ((unsigned)lane < (n & 3u)) {
            unsigned r = rp[base + lane];
            float2 g = gf[r & 0xFFFFu];
            unsigned dl = r >> 16;
            atomicAdd(&s0[dl], g.x); atomicAdd(&s1[dl], g.y); atomicAdd(&scn[dl], 1.f);
        }
    } else {
        // ------------ GEMM waves (w = 0,1,2) ------------
        float* z = zb[w];
        frag_ab bfrag[16];
        #pragma unroll
        for (int f = 0; f < 16; ++f) bfrag[f] = wcb[f * 64 + lane];
        float bcv[4];
        #pragma unroll
        for (int nt = 0; nt < 4; ++nt) bcv[nt] = bc[nt * 16 + c];
        float c20 = c2[0], c21 = c2[1];

        for (int tl = w; tl < n_tiles; tl += 3) {
            int lrow = tl * 16 + c;
            int row = cust0 + lrow;
            const float* xr = x + (size_t)row * D_CUST;
            frag_ab af[4];
            #pragma unroll
            for (int kc = 0; kc < 3; ++kc) {
                float4u lo = *(const float4u*)(xr + kc * 32 + q * 8);
                float4u hi = *(const float4u*)(xr + kc * 32 + q * 8 + 4);
                frag_ab f;
                f[0]=f2bf(lo[0]); f[1]=f2bf(lo[1]); f[2]=f2bf(lo[2]); f[3]=f2bf(lo[3]);
                f[4]=f2bf(hi[0]); f[5]=f2bf(hi[1]); f[6]=f2bf(hi[2]); f[7]=f2bf(hi[3]);
                af[kc] = f;
            }
            {   // tail k = 96..127: only q==0 lanes hold valid k (96..100)
                frag_ab f = {0,0,0,0,0,0,0,0};
                if (q == 0) {
                    float4u lo = *(const float4u*)(xr + 96);
                    f[0]=f2bf(lo[0]); f[1]=f2bf(lo[1]); f[2]=f2bf(lo[2]); f[3]=f2bf(lo[3]);
                    f[4]=f2bf(xr[100]);
                }
                af[3] = f;
            }
            frag_cd acc[4];
            #pragma unroll
            for (int nt = 0; nt < 4; ++nt)
                acc[nt] = (frag_cd){bcv[nt], bcv[nt], bcv[nt], bcv[nt]};
            #pragma unroll
            for (int kc = 0; kc < 4; ++kc)
                #pragma unroll
                for (int nt = 0; nt < 4; ++nt)
                    acc[nt] = __builtin_amdgcn_mfma_f32_16x16x32_bf16(
                        af[kc], bfrag[nt * 4 + kc], acc[nt], 0, 0, 0);

            // relu -> LDS: C[r = q*4+i][col = nt*16+c]
            #pragma unroll
            for (int nt = 0; nt < 4; ++nt)
                #pragma unroll
                for (int i = 0; i < 4; ++i)
                    z[(q * 4 + i) * 68 + nt * 16 + c] = fmaxf(acc[nt][i], 0.f);

            // lane: z-row r=c, h in [q*16, q*16+16); reduce over q via shfl
            float p0 = 0.f, p1 = 0.f;
            #pragma unroll
            for (int j4 = 0; j4 < 4; ++j4) {
                float4u zv = *(const float4u*)(z + c * 68 + q * 16 + j4 * 4);
                float4u b0 = *(const float4u*)(sBt + q * 32 + j4 * 8);
                float4u b1 = *(const float4u*)(sBt + q * 32 + j4 * 8 + 4);
                p0 = fmaf(zv[0], b0[0], p0); p1 = fmaf(zv[0], b0[1], p1);
                p0 = fmaf(zv[1], b0[2], p0); p1 = fmaf(zv[1], b0[3], p1);
                p0 = fmaf(zv[2], b1[0], p0); p1 = fmaf(zv[2], b1[1], p1);
                p0 = fmaf(zv[3], b1[2], p0); p1 = fmaf(zv[3], b1[3], p1);
            }
            p0 += __shfl_xor(p0, 16, 64); p0 += __shfl_xor(p0, 32, 64);
            p1 += __shfl_xor(p1, 16, 64); p1 += __shfl_xor(p1, 32, 64);
            if (q == 0) {
                pbuf[2 * lrow]     = p0 + c20;
                pbuf[2 * lrow + 1] = p1 + c21;
            }
        }
    }
    __syncthreads();

    // epilogue: combine GEMM result with neighbor mean, coalesced write
    for (int cc = t; cc < ncust; cc += 256) {
        float inv = 1.0f / fmaxf(scn[cc], 1.0f);
        out[cust0 + cc] = make_float2(fmaf(s0[cc], inv, pbuf[2 * cc]),
                                      fmaf(s1[cc], inv, pbuf[2 * cc + 1]));
    }
}

// ---------------------------------------------------------------------------
// Fallback-path kernels (direct global atomics) if ws too small for recs.
// ---------------------------------------------------------------------------
__global__ __launch_bounds__(256) void k_scatter_direct(
    const int* __restrict__ src, const int* __restrict__ dst,
    const float2* __restrict__ gf, Accum* __restrict__ A)
{
    int stride = gridDim.x * 256;
    for (int e = blockIdx.x * 256 + threadIdx.x; e < N_EDGE; e += stride) {
        int s = src[e], d = dst[e];
        float2 g = gf[s];
        unsafeAtomicAdd(&A[d].g0, g.x);
        unsafeAtomicAdd(&A[d].g1, g.y);
        unsafeAtomicAdd(&A[d].cnt, 1.0f);
    }
}

__global__ __launch_bounds__(256) void k_mean(
    const Accum* __restrict__ A, float2* __restrict__ mean2)
{
    int i = blockIdx.x * 256 + threadIdx.x;
    if (i < N_CUST) {
        Accum a = A[i];
        float inv = 1.0f / fmaxf(a.cnt, 1.0f);
        mean2[i] = make_float2(a.g0 * inv, a.g1 * inv);
    }
}

__global__ __launch_bounds__(256) void k_gemm(
    const float* __restrict__ x, const float* __restrict__ bc,
    const frag_ab* __restrict__ wcb, const float* __restrict__ Bt,
    const float* __restrict__ c2, const float2* __restrict__ mean2,
    float2* __restrict__ out)
{
    __shared__ float sBt[128];
    __shared__ float zb[4][16 * 68];

    int t = threadIdx.x;
    int w = t >> 6, lane = t & 63;
    int c = lane & 15, q = lane >> 4;
    float* z = zb[w];

    if (t < 128) sBt[t] = Bt[t];
    frag_ab bfrag[16];
    #pragma unroll
    for (int f = 0; f < 16; ++f) bfrag[f] = wcb[f * 64 + lane];
    float bcv[4];
    #pragma unroll
    for (int nt = 0; nt < 4; ++nt) bcv[nt] = bc[nt * 16 + c];
    float c20 = c2[0], c21 = c2[1];
    __syncthreads();

    const int NT = N_CUST / 16;
    for (int tl = blockIdx.x * 4 + w; tl < NT; tl += gridDim.x * 4) {
        int row0 = tl * 16;
        const float* xr = x + (size_t)(row0 + c) * D_CUST;
        frag_ab af[4];
        #pragma unroll
        for (int kc = 0; kc < 3; ++kc) {
            float4u lo = *(const float4u*)(xr + kc * 32 + q * 8);
            float4u hi = *(const float4u*)(xr + kc * 32 + q * 8 + 4);
            frag_ab f;
            f[0]=f2bf(lo[0]); f[1]=f2bf(lo[1]); f[2]=f2bf(lo[2]); f[3]=f2bf(lo[3]);
            f[4]=f2bf(hi[0]); f[5]=f2bf(hi[1]); f[6]=f2bf(hi[2]); f[7]=f2bf(hi[3]);
            af[kc] = f;
        }
        {
            frag_ab f = {0,0,0,0,0,0,0,0};
            if (q == 0) {
                float4u lo = *(const float4u*)(xr + 96);
                f[0]=f2bf(lo[0]); f[1]=f2bf(lo[1]); f[2]=f2bf(lo[2]); f[3]=f2bf(lo[3]);
                f[4]=f2bf(xr[100]);
            }
            af[3] = f;
        }
        frag_cd acc[4];
        #pragma unroll
        for (int nt = 0; nt < 4; ++nt)
            acc[nt] = (frag_cd){bcv[nt], bcv[nt], bcv[nt], bcv[nt]};
        #pragma unroll
        for (int kc = 0; kc < 4; ++kc)
            #pragma unroll
            for (int nt = 0; nt < 4; ++nt)
                acc[nt] = __builtin_amdgcn_mfma_f32_16x16x32_bf16(
                    af[kc], bfrag[nt * 4 + kc], acc[nt], 0, 0, 0);
        #pragma unroll
        for (int nt = 0; nt < 4; ++nt)
            #pragma unroll
            for (int i = 0; i < 4; ++i)
                z[(q * 4 + i) * 68 + nt * 16 + c] = fmaxf(acc[nt][i], 0.f);
        float p0 = 0.f, p1 = 0.f;
        #pragma unroll
        for (int j4 = 0; j4 < 4; ++j4) {
            float4u zv = *(const float4u*)(z + c * 68 + q * 16 + j4 * 4);
            float4u b0 = *(const float4u*)(sBt + q * 32 + j4 * 8);
            float4u b1 = *(const float4u*)(sBt + q * 32 + j4 * 8 + 4);
            p0 = fmaf(zv[0], b0[0], p0); p1 = fmaf(zv[0], b0[1], p1);
            p0 = fmaf(zv[1], b0[2], p0); p1 = fmaf(zv[1], b0[3], p1);
            p0 = fmaf(zv[2], b1[0], p0); p1 = fmaf(zv[2], b1[1], p1);
            p0 = fmaf(zv[3], b1[2], p0); p1 = fmaf(zv[3], b1[3], p1);
        }
        p0 += __shfl_xor(p0, 16, 64); p0 += __shfl_xor(p0, 32, 64);
        p1 += __shfl_xor(p1, 16, 64); p1 += __shfl_xor(p1, 32, 64);
        if (q == 0) {
            float2 m = mean2[row0 + c];
            out[row0 + c] = make_float2(p0 + c20 + m.x, p1 + c21 + m.y);
        }
    }
}

// ---------------------------------------------------------------------------
extern "C" void kernel_launch(void* const* d_in, const int* in_sizes, int n_in,
                              void* d_out, int out_size, void* d_ws, size_t ws_size,
                              hipStream_t stream) {
    const float* x_customer = (const float*)d_in[0];
    const float* x_fund     = (const float*)d_in[1];
    const int*   src_fund   = (const int*)d_in[2];
    const int*   dst_cust   = (const int*)d_in[3];
    const float* W_cust     = (const float*)d_in[4];
    const float* b_cust     = (const float*)d_in[5];
    const float* W_fund     = (const float*)d_in[6];
    const float* b_fund     = (const float*)d_in[7];
    const float* W_l        = (const float*)d_in[8];
    const float* b_l        = (const float*)d_in[9];
    const float* W_r        = (const float*)d_in[10];
    const float* W_out      = (const float*)d_in[11];
    const float* b_out      = (const float*)d_in[12];

    char* ws = (char*)d_ws;
    // fast path layout:
    //   recs @ 0          : 977*5120*4 = 20,008,960
    //   gf   @ 20,008,960 :   400,000
    //   wcb  @ 20,408,960 :    16,384
    //   Bt   @ 20,425,344 :       512
    //   c2   @ 20,425,856 :        64
    //   gcur @ 20,425,920 :   125,056  (977*32*4, padded) -> total 20,550,976
    const size_t NEED_FAST = 20550976ull;

    if (ws_size >= NEED_FAST) {
        unsigned* recs = (unsigned*)(ws);
        float2*   gf   = (float2*)  (ws + 20008960);
        frag_ab*  wcb  = (frag_ab*) (ws + 20408960);
        float*    Bt   = (float*)   (ws + 20425344);
        float*    c2   = (float*)   (ws + 20425856);
        unsigned* gcur = (unsigned*)(ws + 20425920);

        k_gf<<<256, 256, 0, stream>>>(
            x_fund, W_fund, b_fund, W_l, W_r, W_out, W_cust, b_l, b_out,
            gf, wcb, Bt, c2, gcur, nullptr);
        k_reorder<<<NB, 256, 0, stream>>>(src_fund, dst_cust, gcur, recs);
        k_bucket<<<NBKT, 256, 0, stream>>>(
            recs, gcur, gf, x_customer, b_cust, wcb, Bt, c2, (float2*)d_out);
    } else {
        // fallback: A 8,000,000 | mean2 4,000,000 | gf 400,000 | wcb 16,384
        //           | Bt 512 | c2 64 | gcur 125,056 -> 12,542,016
        Accum*    A    = (Accum*)   (ws);
        float2*   mn2  = (float2*)  (ws + 8000000);
        float2*   gf   = (float2*)  (ws + 12000000);
        frag_ab*  wcb  = (frag_ab*) (ws + 12400000);
        float*    Bt   = (float*)   (ws + 12416384);
        float*    c2   = (float*)   (ws + 12416896);
        unsigned* gcur = (unsigned*)(ws + 12416960);

        k_gf<<<256, 256, 0, stream>>>(
            x_fund, W_fund, b_fund, W_l, W_r, W_out, W_cust, b_l, b_out,
            gf, wcb, Bt, c2, gcur, (float4*)A);
        k_scatter_direct<<<2048, 256, 0, stream>>>(src_fund, dst_cust, gf, A);
        k_mean<<<(N_CUST + 255) / 256, 256, 0, stream>>>(A, mn2);
        k_gemm<<<2048, 256, 0, stream>>>(
            x_customer, b_cust, wcb, Bt, c2, mn2, (float2*)d_out);
    }
}